// Round 5
// baseline (120.444 us; speedup 1.0000x reference)
//
#include <hip/hip_runtime.h>
#include <hip/hip_bf16.h>

#define N_NODES 50000
#define N_EDGES 800000
#define DIM 128
#define BCAP 64  // bucket capacity per node (max degree ~38 for this input)

typedef __attribute__((ext_vector_type(8))) short bf16x8;
typedef __attribute__((ext_vector_type(4))) float f32x4;

union BU8 { uint4 u; bf16x8 b; };

static __device__ __forceinline__ ushort f2bf(float f) {
    __hip_bfloat16 h = __float2bfloat16(f);
    return *reinterpret_cast<ushort*>(&h);
}
static __device__ __forceinline__ uint pack2(float a, float b) {
    return (uint)f2bf(a) | ((uint)f2bf(b) << 16);
}
static __device__ __forceinline__ float bflo(uint u) { return __uint_as_float(u << 16); }
static __device__ __forceinline__ float bfhi(uint u) { return __uint_as_float(u & 0xffff0000u); }

// ---------------- zero count+ovfcnt ----------------
__global__ void zero_k(int4* __restrict__ p, int n4) {
    int i = blockIdx.x * blockDim.x + threadIdx.x;
    if (i < n4) p[i] = make_int4(0, 0, 0, 0);
}

// ---------------- W concat + convert: Wcat = [Ws ; Wn] bf16 ----------------
__global__ void cvtW_k(const float* __restrict__ Ws, const float* __restrict__ Wn,
                       ushort* __restrict__ Wcat) {
    int t = blockIdx.x * blockDim.x + threadIdx.x;  // 0..4095
    const float* srcp = (t < 2048) ? Ws : Wn;
    int i = (t & 2047) * 8;
    float4 a = *(const float4*)(srcp + i);
    float4 b = *(const float4*)(srcp + i + 4);
    uint4 r;
    r.x = pack2(a.x, a.y); r.y = pack2(a.z, a.w);
    r.z = pack2(b.x, b.y); r.w = pack2(b.z, b.w);
    *(uint4*)(Wcat + ((t < 2048) ? 0 : 16384) + i) = r;
}

// ---------------- one-pass bucketed CSR ----------------
// srclist[d*64 + pos] = src; overflow (pos>=64) -> ovf list (empty in practice)
__global__ void bucket_k(const int* __restrict__ src, const int* __restrict__ dst,
                         int* __restrict__ count, ushort* __restrict__ srclist,
                         int* __restrict__ ovfcnt, int2* __restrict__ ovf) {
    int e = blockIdx.x * blockDim.x + threadIdx.x;
    if (e >= N_EDGES) return;
    int d = dst[e];
    int s = src[e];
    int pos = atomicAdd(&count[d], 1);
    if (pos < BCAP) {
        srclist[d * BCAP + pos] = (ushort)s;
    } else {
        int o = atomicAdd(ovfcnt, 1);
        ovf[o] = make_int2(s, d);
    }
}

// ---------------- MFMA GEMM: out = x@Ws^T + b (fp32), Yn = x@Wn^T (bf16) --
__global__ __launch_bounds__(256, 2) void mm_k(const float* __restrict__ x,
                                               const ushort* __restrict__ Wcat,
                                               const float* __restrict__ bias,
                                               float* __restrict__ out,
                                               ushort* __restrict__ Yn) {
    __shared__ ushort wlds[32768];  // 64 KB
    int tid  = threadIdx.x;
    int lane = tid & 63;
    int w    = tid >> 6;
    int lr   = lane & 15;
    int g    = lane >> 4;            // k-group 0..3
    int myrow0 = blockIdx.x * 128 + w * 32;

    // ---- load A (fp32) & convert: 2 rowtiles x 4 kfrags ----
    bf16x8 a[2][4];
#pragma unroll
    for (int rt = 0; rt < 2; ++rt) {
        int row = myrow0 + rt * 16 + lr;
        bool ok = row < N_NODES;
        const float* ap = x + (size_t)row * 128;
#pragma unroll
        for (int kf = 0; kf < 4; ++kf) {
            float4 f0 = make_float4(0.f, 0.f, 0.f, 0.f), f1 = f0;
            if (ok) {
                f0 = *(const float4*)(ap + kf * 32 + g * 8);
                f1 = *(const float4*)(ap + kf * 32 + g * 8 + 4);
            }
            BU8 u;
            u.u.x = pack2(f0.x, f0.y); u.u.y = pack2(f0.z, f0.w);
            u.u.z = pack2(f1.x, f1.y); u.u.w = pack2(f1.z, f1.w);
            a[rt][kf] = u.b;
        }
    }

    // ---- stage Wcat into swizzled LDS: chunk c (16B) of row r at c^(r&7) ----
#pragma unroll
    for (int i = 0; i < 16; ++i) {
        int f = i * 256 + tid;
        int r = f >> 4, c = f & 15;
        uint4 v = *(const uint4*)(Wcat + r * 128 + c * 8);
        *(uint4*)(&wlds[r * 128 + ((c ^ (r & 7)) * 8)]) = v;
    }
    __syncthreads();

    // ---- K-loop over 16 col-tiles ----
    f32x4 acc[2][16];
#pragma unroll
    for (int rt = 0; rt < 2; ++rt)
#pragma unroll
        for (int nt = 0; nt < 16; ++nt) acc[rt][nt] = (f32x4){0.f, 0.f, 0.f, 0.f};

#pragma unroll
    for (int nt = 0; nt < 16; ++nt) {
        int row = nt * 16 + lr;
#pragma unroll
        for (int kf = 0; kf < 4; ++kf) {
            int chunk = kf * 4 + g;
            bf16x8 b = *(const bf16x8*)(&wlds[row * 128 + ((chunk ^ (lr & 7)) * 8)]);
            acc[0][nt] = __builtin_amdgcn_mfma_f32_16x16x32_bf16(a[0][kf], b, acc[0][nt], 0, 0, 0);
            acc[1][nt] = __builtin_amdgcn_mfma_f32_16x16x32_bf16(a[1][kf], b, acc[1][nt], 0, 0, 0);
        }
    }

    // ---- epilogue: col<128 -> out(+bias); col>=128 -> Yn bf16 ----
#pragma unroll
    for (int nt = 0; nt < 16; ++nt) {
        int col = nt * 16 + lr;
        float bv = (col < 128) ? bias[col] : 0.f;
#pragma unroll
        for (int rt = 0; rt < 2; ++rt) {
            int rowb = myrow0 + rt * 16 + g * 4;
#pragma unroll
            for (int j = 0; j < 4; ++j) {
                int row = rowb + j;
                if (row < N_NODES) {
                    if (col < 128)
                        out[(size_t)row * 128 + col] = acc[rt][nt][j] + bv;
                    else
                        Yn[(size_t)row * 128 + (col - 128)] = f2bf(acc[rt][nt][j]);
                }
            }
        }
    }
}

// ---------------- Aggregate: out[v] += (1/deg) * sum Yn[src] ----------------
// One wave per node; bucket = one coalesced 128B read; 4 edges/iter gather.
__global__ __launch_bounds__(256) void agg2_k(const ushort* __restrict__ Yn,
                                              const int* __restrict__ count,
                                              const ushort* __restrict__ srclist,
                                              float* __restrict__ out) {
    int wid = blockIdx.x * 4 + (threadIdx.x >> 6);
    if (wid >= N_NODES) return;
    int lane = threadIdx.x & 63;
    int g = lane >> 4;          // edge slot within quad
    int c8 = (lane & 15) * 8;   // col base (8 bf16 = 16B)
    int deg = count[wid];
    int m = (deg < BCAP) ? deg : BCAP;
    int sreg = (lane < m) ? (int)srclist[wid * BCAP + lane] : 0;

    float acc0 = 0.f, acc1 = 0.f, acc2 = 0.f, acc3 = 0.f;
    float acc4 = 0.f, acc5 = 0.f, acc6 = 0.f, acc7 = 0.f;

#define ACC8(v)                                        \
    do {                                               \
        acc0 += bflo(v.x); acc1 += bfhi(v.x);          \
        acc2 += bflo(v.y); acc3 += bfhi(v.y);          \
        acc4 += bflo(v.z); acc5 += bfhi(v.z);          \
        acc6 += bflo(v.w); acc7 += bfhi(v.w);          \
    } while (0)

    int j = 0;
    for (; j + 4 <= m; j += 4) {
        int s = __shfl(sreg, j + g);
        uint4 v = *(const uint4*)(Yn + (size_t)s * 128 + c8);
        ACC8(v);
    }
    if (j < m) {
        int jj = j + g;
        bool valid = jj < m;
        int s = __shfl(sreg, valid ? jj : j);
        uint4 v = *(const uint4*)(Yn + (size_t)s * 128 + c8);
        if (valid) ACC8(v);
    }
#undef ACC8

#define RED(a) do { a += __shfl_xor(a, 16); a += __shfl_xor(a, 32); } while (0)
    RED(acc0); RED(acc1); RED(acc2); RED(acc3);
    RED(acc4); RED(acc5); RED(acc6); RED(acc7);
#undef RED

    if (lane < 16) {
        float scale = 1.0f / (float)(deg > 0 ? deg : 1);
        float* orow = out + (size_t)wid * 128 + c8;
        float4 o0 = *(const float4*)(orow);
        float4 o1 = *(const float4*)(orow + 4);
        o0.x += scale * acc0; o0.y += scale * acc1;
        o0.z += scale * acc2; o0.w += scale * acc3;
        o1.x += scale * acc4; o1.y += scale * acc5;
        o1.z += scale * acc6; o1.w += scale * acc7;
        *(float4*)(orow) = o0;
        *(float4*)(orow + 4) = o1;
    }
}

// ---------------- Overflow edges (deg > BCAP): atomic adds; empty here ------
__global__ void ovf_k(const ushort* __restrict__ Yn, const int* __restrict__ count,
                      const int* __restrict__ ovfcnt, const int2* __restrict__ ovf,
                      float* __restrict__ out) {
    int n = *ovfcnt;
    for (int i = blockIdx.x; i < n; i += gridDim.x) {
        int2 e = ovf[i];
        int s = e.x, d = e.y;
        float scale = 1.0f / (float)max(count[d], 1);
        int c = threadIdx.x;  // 128 threads
        float v = bflo((uint)Yn[(size_t)s * 128 + c] << 0) ;
        v = __uint_as_float(((uint)Yn[(size_t)s * 128 + c]) << 16);
        atomicAdd(&out[(size_t)d * 128 + c], scale * v);
    }
}

extern "C" void kernel_launch(void* const* d_in, const int* in_sizes, int n_in,
                              void* d_out, int out_size, void* d_ws, size_t ws_size,
                              hipStream_t stream) {
    const float* x       = (const float*)d_in[0];
    const float* W_self  = (const float*)d_in[1];
    const float* b_self  = (const float*)d_in[2];
    const float* W_neigh = (const float*)d_in[3];
    // d_in[4] = edge_w: unused (== 1/max(deg(dst),1), recomputed from counts)
    const int* src = (const int*)d_in[5];
    const int* dst = (const int*)d_in[6];
    float* out = (float*)d_out;

    // ws layout (bytes)
    char* ws = (char*)d_ws;
    ushort* Yn      = (ushort*)(ws);              // 12,800,000
    ushort* Wcat    = (ushort*)(ws + 12800000);   //     65,536
    int*    count   = (int*)(ws + 12865536);      //    200,000 (+ ovfcnt @ +200000)
    int*    ovfcnt  = count + N_NODES;
    ushort* srclist = (ushort*)(ws + 13065552);   //  6,400,000 (50000*64*2)
    int2*   ovf     = (int2*)(ws + 19465552);     //  6,400,000 worst case

    const int nedge = (N_EDGES + 255) / 256;  // 3125

    // zero count + ovfcnt: 50004 ints -> 12501 int4
    zero_k<<<49, 256, 0, stream>>>((int4*)count, 12501);

    cvtW_k<<<16, 256, 0, stream>>>(W_self, W_neigh, Wcat);

    // one-pass CSR bucket build (replaces degree+scanA+scanBC+fill)
    bucket_k<<<nedge, 256, 0, stream>>>(src, dst, count, srclist, ovfcnt, ovf);

    // dense: out = x@Ws^T + b (fp32), Yn = x@Wn^T (bf16)
    mm_k<<<(N_NODES + 127) / 128, 256, 0, stream>>>(x, Wcat, b_self, out, Yn);

    // sparse: out[v] += (1/deg) * sum_{src->v} Yn[src]
    agg2_k<<<(N_NODES + 3) / 4, 256, 0, stream>>>(Yn, count, srclist, out);

    // overflow edges (deg > 64): none for this input, ~no-op
    ovf_k<<<64, 128, 0, stream>>>(Yn, count, ovfcnt, ovf, out);
}